// Round 9
// baseline (95.085 us; speedup 1.0000x reference)
//
#include <hip/hip_runtime.h>
#include <math.h>

#define F 8
#define C 4096
#define NOFF 28             // i<j factor pairs (diag G_ii closed-form)
#define NPAIR 36
#define EPSF 1e-8f

#define NSUP 64             // 64 supers of 64 indices
#define NTILE (NSUP * (NSUP + 1) / 2)   // 2080 upper-incl-diag tiles
#define NTB (NTILE / 4)     // 520 blocks, 4 independent waves each

#define RS_QC 32            // rs kernel: 32 q-chunks of 128
#define NSB 128             // sred blocks
#define SOUT_N 88           // D[36]|T[8]|Q[8]|T0[8]|G[28]

// ws: part[RS_QC][8][4096] (4 MB) | gpart[NTILE][28] (233 KB) | sout[128][88]
#define WS_PART (RS_QC * F * C)
#define WS_GP   (NTILE * NOFF)

__device__ __forceinline__ float wave_reduce(float v) {
    #pragma unroll
    for (int off = 32; off > 0; off >>= 1) v += __shfl_down(v, off, 64);
    return v;
}

__host__ __device__ constexpr int PK(int i, int j) {   // i<j pair index, lexicographic
    return i * 7 - i * (i - 1) / 2 + (j - i - 1);
}

// Gram-only kernel. One 64x64 super-tile per WAVE (4 independent waves per
// block, no barriers). Ordered-sum identity: full = 2*upper + diag (p==q
// terms are zero). Each wave stages its 64-q slice into a private 2 KB LDS
// region once (8 coalesced loads + 8 ds_writes), then the entire sweep is
// ds_read_b64 at compile-time offsets + FMA: NO memory-pipe waits in the
// loop -- this removes the per-group load->drain serialization that pinned
// rounds 2-8 at ~40 us across all three global/SMEM q-load paths.
// Live set ~60 VGPR (g28+xp8+aA8+aB8+buf8) co-designed for the 64-reg tier.
__global__ __launch_bounds__(256) void gram_kernel(const float* __restrict__ x,
                                                   float* __restrict__ gpart) {
    __shared__ __align__(16) float xs[4 * F * 64];   // 8 KB, 2 KB per wave
    const int tid  = threadIdx.x;
    const int lane = tid & 63;
    const int wave = tid >> 6;
    const int t    = blockIdx.x * 4 + wave;          // tile id in [0, 2080)

    // decode t -> (a, b), a<=b, row a has 64-a tiles. cum(a) = 64a - a(a-1)/2
    int a = (int)floorf(64.5f - sqrtf(4160.25f - 2.0f * (float)t));
    while ((64 * (a + 1) - (a + 1) * a / 2) <= t) ++a;      // guard rounding
    while ((64 * a - a * (a - 1) / 2) > t) --a;
    const int b = a + (t - (64 * a - a * (a - 1) / 2));
    const int p  = a * 64 + lane;
    const int q0 = b * 64;
    const float w = (a == b) ? 1.0f : 2.0f;

    const int woff = wave * (F * 64);
    #pragma unroll
    for (int f = 0; f < F; ++f)
        xs[woff + f * 64 + lane] = x[f * C + q0 + lane];     // stage q-slice

    float xp[F];
    #pragma unroll
    for (int f = 0; f < F; ++f) xp[f] = x[f * C + p];

    float g[NOFF];
    #pragma unroll
    for (int k = 0; k < NOFF; ++k) g[k] = 0.0f;

    // 32 groups of 2 q; all LDS reads are wave-uniform broadcasts with
    // immediate offsets. Factors processed 4-at-a-time to cap live regs.
    #pragma unroll 4
    for (int g2 = 0; g2 < 32; ++g2) {
        float aA[F], aB[F];
        #pragma unroll
        for (int f = 0; f < 4; ++f) {
            const float2 v = *(const float2*)&xs[woff + f * 64 + 2 * g2];
            aA[f] = v.x - xp[f];
            aB[f] = v.y - xp[f];
        }
        #pragma unroll
        for (int i = 0; i < 4; ++i)
            #pragma unroll
            for (int j = i + 1; j < 4; ++j) {
                const int k = PK(i, j);
                g[k] = __builtin_fmaf(__builtin_fabsf(aA[i]), __builtin_fabsf(aA[j]), g[k]);
                g[k] = __builtin_fmaf(__builtin_fabsf(aB[i]), __builtin_fabsf(aB[j]), g[k]);
            }
        #pragma unroll
        for (int f = 4; f < 8; ++f) {
            const float2 v = *(const float2*)&xs[woff + f * 64 + 2 * g2];
            aA[f] = v.x - xp[f];
            aB[f] = v.y - xp[f];
        }
        #pragma unroll
        for (int i = 0; i < 8; ++i)
            #pragma unroll
            for (int j = (i + 1 > 4 ? i + 1 : 4); j < 8; ++j) {
                const int k = PK(i, j);
                g[k] = __builtin_fmaf(__builtin_fabsf(aA[i]), __builtin_fabsf(aA[j]), g[k]);
                g[k] = __builtin_fmaf(__builtin_fabsf(aB[i]), __builtin_fabsf(aB[j]), g[k]);
            }
    }

    #pragma unroll
    for (int k = 0; k < NOFF; ++k) g[k] = wave_reduce(g[k] * w);
    if (lane == 0) {
        #pragma unroll
        for (int k = 0; k < NOFF; ++k) gpart[t * NOFF + k] = g[k];
    }
}

// rs kernel: s_f(p) partials. Block (pb, qc): 256 p-lanes sweep a shared
// 128-q slice staged in 4 KB LDS (one barrier). 2-q groups, b64 broadcast
// reads, |d0|+|d1| folds into VOP3 source mods. ~30 VGPR -> deep occupancy.
__global__ __launch_bounds__(256) void rs_kernel(const float* __restrict__ x,
                                                 float* __restrict__ part) {
    __shared__ __align__(16) float xs[F * 128];      // 4 KB
    const int tid = threadIdx.x;
    const int pb  = blockIdx.x & 15;
    const int qc  = blockIdx.x >> 4;
    const int p   = pb * 256 + tid;

    {   // stage: thread t -> factor t>>5, float4 t&31
        const int f = tid >> 5, q4 = tid & 31;
        ((float4*)xs)[tid] = ((const float4*)x)[f * (C / 4) + qc * 32 + q4];
    }

    float xp[F];
    #pragma unroll
    for (int f = 0; f < F; ++f) xp[f] = x[f * C + p];
    float rs[F];
    #pragma unroll
    for (int f = 0; f < F; ++f) rs[f] = 0.0f;

    __syncthreads();

    #pragma unroll 8
    for (int g2 = 0; g2 < 64; ++g2) {
        #pragma unroll
        for (int f = 0; f < F; ++f) {
            const float2 v = *(const float2*)&xs[f * 128 + 2 * g2];
            const float d0 = v.x - xp[f];
            const float d1 = v.y - xp[f];
            rs[f] += __builtin_fabsf(d0) + __builtin_fabsf(d1);
        }
    }

    #pragma unroll
    for (int f = 0; f < F; ++f) part[(qc * F + f) * C + p] = rs[f];
}

// 128 blocks x 256 threads. Block b owns 32 p: reduce 32 q-chunk rs-partials
// -> s_f(p), form D/T and moments Q/T0; threads [64,176) reduce this block's
// 17-row slice of the 2080 gram partials.
__global__ __launch_bounds__(256) void sred_kernel(const float* __restrict__ x,
                                                   const float* __restrict__ part,
                                                   const float* __restrict__ gpart,
                                                   float* __restrict__ sout) {
    __shared__ float sp[8][F][32];
    __shared__ float gred[NOFF][4];
    const int tid = threadIdx.x;
    const int pi  = tid & 31;
    const int qg  = tid >> 5;
    const int b   = blockIdx.x;
    const int p   = b * 32 + pi;

    float acc[F];
    #pragma unroll
    for (int f = 0; f < F; ++f) acc[f] = 0.0f;
    #pragma unroll
    for (int qq = 0; qq < RS_QC / 8; ++qq) {
        const int qc = qg * (RS_QC / 8) + qq;
        #pragma unroll
        for (int f = 0; f < F; ++f) acc[f] += part[(qc * F + f) * C + p];
    }
    #pragma unroll
    for (int f = 0; f < F; ++f) sp[qg][f][pi] = acc[f];
    __syncthreads();

    // gram partial slice: rows b*17 .. b*17+16 (bounds-guarded), 4-way each
    if (tid >= 64 && tid < 64 + NOFF * 4) {
        const int idx = tid - 64, gk = idx >> 2, c = idx & 3;
        float s = 0.0f;
        #pragma unroll
        for (int i = 0; i < 5; ++i) {
            const int rl = c + 4 * i;
            const int r  = b * 17 + rl;
            if (rl < 17 && r < NTILE) s += gpart[r * NOFF + gk];
        }
        gred[gk][c] = s;
    }

    if (tid < 64) {
        float vals[60];                 // D[36] | T[8] | Q[8] | T0[8]
        if (tid < 32) {
            float sv[F], xv[F];
            #pragma unroll
            for (int f = 0; f < F; ++f) {
                float s = 0.0f;
                #pragma unroll
                for (int g2 = 0; g2 < 8; ++g2) s += sp[g2][f][pi];
                sv[f] = s;
                xv[f] = x[f * C + p];
            }
            int k = 0;
            #pragma unroll
            for (int i = 0; i < F; ++i)
                #pragma unroll
                for (int j = i; j < F; ++j) { vals[k] = sv[i] * sv[j]; ++k; }
            #pragma unroll
            for (int f = 0; f < F; ++f) vals[36 + f] = sv[f];
            #pragma unroll
            for (int f = 0; f < F; ++f) vals[44 + f] = xv[f] * xv[f];
            #pragma unroll
            for (int f = 0; f < F; ++f) vals[52 + f] = xv[f];
        } else {
            #pragma unroll
            for (int k = 0; k < 60; ++k) vals[k] = 0.0f;
        }
        #pragma unroll
        for (int k = 0; k < 60; ++k) vals[k] = wave_reduce(vals[k]);
        if (tid == 0) {
            #pragma unroll
            for (int k = 0; k < 60; ++k) sout[b * SOUT_N + k] = vals[k];
        }
    }
    __syncthreads();
    if (tid < NOFF)
        sout[b * SOUT_N + 60 + tid] =
            gred[tid][0] + gred[tid][1] + gred[tid][2] + gred[tid][3];
}

__global__ __launch_bounds__(256) void finish_kernel(const float* __restrict__ sout,
                                                     float* __restrict__ out) {
    // A: D[0,36) | T[36,44) | Q[44,52) | T0[52,60) | G_offdiag[60,88)
    __shared__ float fA[SOUT_N][2];
    __shared__ float A[SOUT_N];
    const int tid = threadIdx.x;
    if (tid < SOUT_N * 2) {
        const int col = tid >> 1, h = tid & 1;
        float s = 0.0f;
        #pragma unroll 16
        for (int i = 0; i < NSB / 2; ++i)
            s += sout[(h * (NSB / 2) + i) * SOUT_N + col];
        fA[col][h] = s;
    }
    __syncthreads();
    if (tid < SOUT_N) A[tid] = fA[tid][0] + fA[tid][1];
    __syncthreads();
    if (tid == 0) {
        const float invC  = 1.0f / (float)C;   // 2^-12, exact
        const float invC2 = invC * invC;       // 2^-24, exact
        float dcov[NPAIR], diag[F];
        int k = 0, ko = 0;
        for (int i = 0; i < F; ++i)
            for (int j = i; j < F; ++j) {
                float G;
                if (i == j) {
                    // sum_pq (x_p - x_q)^2 = 2C*sum(x^2) - 2*(sum x)^2
                    G = 2.0f * (float)C * A[44 + i] - 2.0f * A[52 + i] * A[52 + i];
                } else {
                    G = A[60 + ko]; ++ko;
                }
                // S_ij = G/C^2 - 2 D/C^3 + T_i T_j / C^4
                const float S = G * invC2 - 2.0f * A[k] * invC2 * invC
                              + (A[36 + i] * invC2) * (A[36 + j] * invC2);
                const float dc = __builtin_amdgcn_sqrtf(fmaxf(S, 0.0f) + EPSF);
                dcov[k] = dc;
                if (i == j) diag[i] = dc;
                ++k;
            }
        float cor = 0.0f;
        k = 0;
        for (int i = 0; i < F; ++i)
            for (int j = i; j < F; ++j) {
                if (j > i)
                    cor += dcov[k] * __builtin_amdgcn_rcpf(
                               __builtin_amdgcn_sqrtf(diag[i] * diag[j] + EPSF));
                ++k;
            }
        out[0] = cor;
    }
}

extern "C" void kernel_launch(void* const* d_in, const int* in_sizes, int n_in,
                              void* d_out, int out_size, void* d_ws, size_t ws_size,
                              hipStream_t stream) {
    const float* x = (const float*)d_in[0];
    float* part  = (float*)d_ws;
    float* gpart = part + WS_PART;
    float* sout  = gpart + WS_GP;
    float* out   = (float*)d_out;

    hipLaunchKernelGGL(gram_kernel,   dim3(NTB),     dim3(256), 0, stream, x, gpart);
    hipLaunchKernelGGL(rs_kernel,     dim3(16 * RS_QC), dim3(256), 0, stream, x, part);
    hipLaunchKernelGGL(sred_kernel,   dim3(NSB),     dim3(256), 0, stream, x, part, gpart, sout);
    hipLaunchKernelGGL(finish_kernel, dim3(1),       dim3(256), 0, stream, sout, out);
}

// Round 10
// 93.575 us; speedup vs baseline: 1.0161x; 1.0161x over previous
//
#include <hip/hip_runtime.h>
#include <math.h>

#define F 8
#define C 4096
#define NOFF 28             // i<j factor pairs (diag G_ii closed-form)
#define NPAIR 36
#define EPSF 1e-8f

#define NSUP 64             // 64 blocks of 64 indices
#define NTILE (NSUP * (NSUP + 1) / 2)   // 2080 tiles, a<=b
#define NTB (NTILE / 4)     // 520 blocks, 4 independent waves

#define NCHUNK 64           // rs partial chunks (one per 64-q block)
#define NSB 128             // sred blocks
#define SOUT_N 88           // D[36]|T[8]|Q[8]|T0[8]|G[28]

// ws: part[64][8][4096] (8 MB) | gpart[2080][28] (233 KB) | sout[128][88]
#define WS_PART (NCHUNK * F * C)
#define WS_GP   (NTILE * NOFF)

__device__ __forceinline__ float wave_reduce(float v) {
    #pragma unroll
    for (int off = 32; off > 0; off >>= 1) v += __shfl_down(v, off, 64);
    return v;
}

__host__ __device__ constexpr int PK(int i, int j) {   // i<j pair index
    return i * 7 - i * (i - 1) / 2 + (j - i - 1);
}

// One 64x64 super-tile per WAVE; 4 independent waves/block, NO barriers.
// full = 2*upper + diag (p==q terms vanish). Both 64-slices staged in the
// wave's private 4 KB LDS region; all inner-loop reads are wave-uniform
// ds_read broadcasts at immediate offsets. rs is fused: sweep1 gives row
// sums for block a over chunk b (with the gram FMAs); sweep2 (rs-only,
// off-diag tiles) gives row sums for block b over chunk a. Every
// (chunk, row) cell of part[] is written exactly once across tiles.
__global__ __launch_bounds__(256) void gramrs_kernel(const float* __restrict__ x,
                                                     float* __restrict__ part,
                                                     float* __restrict__ gpart) {
    __shared__ __align__(16) float xs[4 * 2 * F * 64];   // 16 KB: per wave A|B slices
    const int tid  = threadIdx.x;
    const int lane = tid & 63;
    const int wave = tid >> 6;
    const int t    = blockIdx.x * 4 + wave;              // tile in [0, 2080)

    // decode t -> (a, b), a<=b; row a holds 64-a tiles
    int a = (int)floorf(64.5f - sqrtf(4160.25f - 2.0f * (float)t));
    while ((64 * (a + 1) - (a + 1) * a / 2) <= t) ++a;
    while ((64 * a - a * (a - 1) / 2) > t) --a;
    const int b  = a + (t - (64 * a - a * (a - 1) / 2));
    const int pA = a * 64 + lane;
    const int pB = b * 64 + lane;
    const float w = (a == b) ? 1.0f : 2.0f;

    float* xsA = xs + wave * (2 * F * 64);
    float* xsB = xsA + F * 64;
    #pragma unroll
    for (int f = 0; f < F; ++f) {
        xsA[f * 64 + lane] = x[f * C + pA];
        xsB[f * 64 + lane] = x[f * C + pB];
    }

    float xp[F];
    #pragma unroll
    for (int f = 0; f < F; ++f) xp[f] = x[f * C + pA];

    float g[NOFF];
    #pragma unroll
    for (int k = 0; k < NOFF; ++k) g[k] = 0.0f;
    float rs[F];
    #pragma unroll
    for (int f = 0; f < F; ++f) rs[f] = 0.0f;

    // sweep 1: lanes own rows of block a, q runs over block b.
    #pragma unroll 4
    for (int g2 = 0; g2 < 32; ++g2) {
        float aA[F], aB[F];
        #pragma unroll
        for (int f = 0; f < F; ++f) {
            const float2 v = *(const float2*)&xsB[f * 64 + 2 * g2];
            aA[f] = v.x - xp[f];
            aB[f] = v.y - xp[f];
            rs[f] += __builtin_fabsf(aA[f]) + __builtin_fabsf(aB[f]);
        }
        int k = 0;
        #pragma unroll
        for (int i = 0; i < F; ++i)
            #pragma unroll
            for (int j = i + 1; j < F; ++j) {
                g[k] = __builtin_fmaf(__builtin_fabsf(aA[i]), __builtin_fabsf(aA[j]), g[k]);
                g[k] = __builtin_fmaf(__builtin_fabsf(aB[i]), __builtin_fabsf(aB[j]), g[k]);
                ++k;
            }
    }

    // rs rows of a over chunk b (coalesced: lane = consecutive p)
    #pragma unroll
    for (int f = 0; f < F; ++f) part[(b * F + f) * C + pA] = rs[f];

    // gram: weight, wave-reduce, 28 stores
    #pragma unroll
    for (int k = 0; k < NOFF; ++k) g[k] = wave_reduce(g[k] * w);
    if (lane == 0) {
        #pragma unroll
        for (int k = 0; k < NOFF; ++k) gpart[t * NOFF + k] = g[k];
    }

    // sweep 2 (off-diag only): lanes own rows of block b, q over block a.
    if (a != b) {
        float xq[F];
        #pragma unroll
        for (int f = 0; f < F; ++f) xq[f] = x[f * C + pB];
        float rsB[F];
        #pragma unroll
        for (int f = 0; f < F; ++f) rsB[f] = 0.0f;
        #pragma unroll 4
        for (int g2 = 0; g2 < 32; ++g2) {
            #pragma unroll
            for (int f = 0; f < F; ++f) {
                const float2 v = *(const float2*)&xsA[f * 64 + 2 * g2];
                const float d0 = v.x - xq[f];
                const float d1 = v.y - xq[f];
                rsB[f] += __builtin_fabsf(d0) + __builtin_fabsf(d1);
            }
        }
        #pragma unroll
        for (int f = 0; f < F; ++f) part[(a * F + f) * C + pB] = rsB[f];
    }
}

// 128 blocks x 256 threads. Block b owns 32 p: reduce 64 rs-chunks ->
// s_f(p); form D/T and x-moments Q/T0; threads [64,176) reduce this
// block's 17-row slice of the 2080 gram partials.
__global__ __launch_bounds__(256) void sred_kernel(const float* __restrict__ x,
                                                   const float* __restrict__ part,
                                                   const float* __restrict__ gpart,
                                                   float* __restrict__ sout) {
    __shared__ float sp[8][F][32];
    __shared__ float gred[NOFF][4];
    const int tid = threadIdx.x;
    const int pi  = tid & 31;
    const int qg  = tid >> 5;
    const int b   = blockIdx.x;
    const int p   = b * 32 + pi;

    float acc[F];
    #pragma unroll
    for (int f = 0; f < F; ++f) acc[f] = 0.0f;
    #pragma unroll 4
    for (int qq = 0; qq < NCHUNK / 8; ++qq) {
        const int qc = qg * (NCHUNK / 8) + qq;
        #pragma unroll
        for (int f = 0; f < F; ++f) acc[f] += part[(qc * F + f) * C + p];
    }
    #pragma unroll
    for (int f = 0; f < F; ++f) sp[qg][f][pi] = acc[f];
    __syncthreads();

    if (tid >= 64 && tid < 64 + NOFF * 4) {
        const int idx = tid - 64, gk = idx >> 2, c = idx & 3;
        float s = 0.0f;
        #pragma unroll
        for (int i = 0; i < 5; ++i) {
            const int rl = c + 4 * i;
            const int r  = b * 17 + rl;
            if (rl < 17 && r < NTILE) s += gpart[r * NOFF + gk];
        }
        gred[gk][c] = s;
    }

    if (tid < 64) {
        float vals[60];                 // D[36] | T[8] | Q[8] | T0[8]
        if (tid < 32) {
            float sv[F], xv[F];
            #pragma unroll
            for (int f = 0; f < F; ++f) {
                float s = 0.0f;
                #pragma unroll
                for (int g2 = 0; g2 < 8; ++g2) s += sp[g2][f][pi];
                sv[f] = s;
                xv[f] = x[f * C + p];
            }
            int k = 0;
            #pragma unroll
            for (int i = 0; i < F; ++i)
                #pragma unroll
                for (int j = i; j < F; ++j) { vals[k] = sv[i] * sv[j]; ++k; }
            #pragma unroll
            for (int f = 0; f < F; ++f) vals[36 + f] = sv[f];
            #pragma unroll
            for (int f = 0; f < F; ++f) vals[44 + f] = xv[f] * xv[f];
            #pragma unroll
            for (int f = 0; f < F; ++f) vals[52 + f] = xv[f];
        } else {
            #pragma unroll
            for (int k = 0; k < 60; ++k) vals[k] = 0.0f;
        }
        #pragma unroll
        for (int k = 0; k < 60; ++k) vals[k] = wave_reduce(vals[k]);
        if (tid == 0) {
            #pragma unroll
            for (int k = 0; k < 60; ++k) sout[b * SOUT_N + k] = vals[k];
        }
    }
    __syncthreads();
    if (tid < NOFF)
        sout[b * SOUT_N + 60 + tid] =
            gred[tid][0] + gred[tid][1] + gred[tid][2] + gred[tid][3];
}

__global__ __launch_bounds__(256) void finish_kernel(const float* __restrict__ sout,
                                                     float* __restrict__ out) {
    // A: D[0,36) | T[36,44) | Q[44,52) | T0[52,60) | G_offdiag[60,88)
    __shared__ float fA[SOUT_N][2];
    __shared__ float A[SOUT_N];
    const int tid = threadIdx.x;
    if (tid < SOUT_N * 2) {
        const int col = tid >> 1, h = tid & 1;
        float s = 0.0f;
        #pragma unroll 16
        for (int i = 0; i < NSB / 2; ++i)
            s += sout[(h * (NSB / 2) + i) * SOUT_N + col];
        fA[col][h] = s;
    }
    __syncthreads();
    if (tid < SOUT_N) A[tid] = fA[tid][0] + fA[tid][1];
    __syncthreads();
    if (tid == 0) {
        const float invC  = 1.0f / (float)C;   // 2^-12, exact
        const float invC2 = invC * invC;       // 2^-24, exact
        float dcov[NPAIR], diag[F];
        int k = 0, ko = 0;
        for (int i = 0; i < F; ++i)
            for (int j = i; j < F; ++j) {
                float G;
                if (i == j) {
                    // sum_pq (x_p - x_q)^2 = 2C*sum(x^2) - 2*(sum x)^2
                    G = 2.0f * (float)C * A[44 + i] - 2.0f * A[52 + i] * A[52 + i];
                } else {
                    G = A[60 + ko]; ++ko;
                }
                // S_ij = G/C^2 - 2 D/C^3 + T_i T_j / C^4
                const float S = G * invC2 - 2.0f * A[k] * invC2 * invC
                              + (A[36 + i] * invC2) * (A[36 + j] * invC2);
                const float dc = __builtin_amdgcn_sqrtf(fmaxf(S, 0.0f) + EPSF);
                dcov[k] = dc;
                if (i == j) diag[i] = dc;
                ++k;
            }
        float cor = 0.0f;
        k = 0;
        for (int i = 0; i < F; ++i)
            for (int j = i; j < F; ++j) {
                if (j > i)
                    cor += dcov[k] * __builtin_amdgcn_rcpf(
                               __builtin_amdgcn_sqrtf(diag[i] * diag[j] + EPSF));
                ++k;
            }
        out[0] = cor;
    }
}

extern "C" void kernel_launch(void* const* d_in, const int* in_sizes, int n_in,
                              void* d_out, int out_size, void* d_ws, size_t ws_size,
                              hipStream_t stream) {
    const float* x = (const float*)d_in[0];
    float* part  = (float*)d_ws;
    float* gpart = part + WS_PART;
    float* sout  = gpart + WS_GP;
    float* out   = (float*)d_out;

    hipLaunchKernelGGL(gramrs_kernel, dim3(NTB), dim3(256), 0, stream, x, part, gpart);
    hipLaunchKernelGGL(sred_kernel,   dim3(NSB), dim3(256), 0, stream, x, part, gpart, sout);
    hipLaunchKernelGGL(finish_kernel, dim3(1),   dim3(256), 0, stream, sout, out);
}

// Round 11
// 76.598 us; speedup vs baseline: 1.2413x; 1.2216x over previous
//
#include <hip/hip_runtime.h>
#include <math.h>

#define F 8
#define C 4096
#define NPAIR 36
#define EPSF 1e-8f

#define QCH 128              // q per block
#define NQC (C / QCH)        // 32 q-chunks
#define NPG 32               // p-groups of 128 (4 waves x 32 p)
#define NBLK (NPG * NQC)     // 1024 blocks = 4/CU
#define XSROW 132            // 128 + 4 pad: 16B-aligned rows + bank spread

#define NSB 128              // sred blocks
#define SO 116               // sout: D[36] | T[8] | G_b0[36] | G_b1[36]

// ws: part[NQC][F][C] rs-partials (4 MB) | gpart[NBLK][256] C-frags (1 MB) | sout
#define WS_PART (NQC * F * C)
#define WS_GP   (NBLK * 256)

typedef __attribute__((ext_vector_type(8))) short short8v;
typedef __attribute__((ext_vector_type(4))) float f32x4;

__device__ __forceinline__ float wave_reduce(float v) {
    #pragma unroll
    for (int off = 32; off > 0; off >>= 1) v += __shfl_down(v, off, 64);
    return v;
}

// MFMA gram + VALU rs, fused. Wave = 32 p x 128 q. Lane decode:
//   f = lane&7 (factor), b = bit3 (p-batch: A-row f+8b), hi = bit4 (p-octet),
//   qq = bit5 (q parity) -> lane's 8 A-elements are |d_f(p0..p0+7, q)| for
//   ONE q per step. Same frag as A and B => C = sum |d||d|^T: blocks
//   [0:8,0:8] and [8:16,8:16] are the two p-batches' grams (any internal
//   k-mapping works -- the sum over k is enumeration-invariant); cross
//   blocks are garbage, never read. rs stays in VALU (abs folds into
//   source modifiers), combined across qq partners via shfl_xor(32).
__global__ __launch_bounds__(256) void gramrs_kernel(const float* __restrict__ x,
                                                     float* __restrict__ part,
                                                     float* __restrict__ gpart) {
    __shared__ __align__(16) float xs[F * XSROW];   // 4.2 KB q-slice
    __shared__ float red[4 * 256];                  // 4 KB C-frag reduce
    const int tid  = threadIdx.x;
    const int lane = tid & 63;
    const int wave = tid >> 6;
    const int pg = blockIdx.x >> 5;                 // NQC == 32
    const int qc = blockIdx.x & 31;
    const int Q0 = qc * QCH;

    {   // stage q-slice: 8 factors x 32 float4 = 256 threads, one each
        const int sf = tid >> 5, si = tid & 31;
        *(float4*)(xs + sf * XSROW + 4 * si) =
            *(const float4*)(x + sf * C + Q0 + 4 * si);
    }

    const int f  = lane & 7;
    const int b  = (lane >> 3) & 1;
    const int hi = (lane >> 4) & 1;
    const int qq = (lane >> 5) & 1;
    const int p0 = (pg * 4 + wave) * 32 + 16 * b + 8 * hi;

    float xp[8];
    *(float4*)&xp[0] = *(const float4*)(x + f * C + p0);
    *(float4*)&xp[4] = *(const float4*)(x + f * C + p0 + 4);

    f32x4 acc = {0.f, 0.f, 0.f, 0.f};
    float rs[8];
    #pragma unroll
    for (int j = 0; j < 8; ++j) rs[j] = 0.f;

    __syncthreads();

    const float* xrow = xs + f * XSROW + qq;
    #pragma unroll 4
    for (int s = 0; s < QCH / 2; ++s) {
        const float xq = xrow[2 * s];               // lane's one q this step
        float d[8];
        #pragma unroll
        for (int j = 0; j < 8; ++j) {
            d[j] = xq - xp[j];
            rs[j] += __builtin_fabsf(d[j]);         // abs = VOP3 src modifier
        }
        union { unsigned u[4]; short8v v; } fr;
        #pragma unroll
        for (int t = 0; t < 4; ++t)
            asm("v_cvt_pk_bf16_f32 %0, abs(%1), abs(%2)"
                : "=v"(fr.u[t]) : "v"(d[2 * t]), "v"(d[2 * t + 1]));
        acc = __builtin_amdgcn_mfma_f32_16x16x32_bf16(fr.v, fr.v, acc, 0, 0, 0);
    }

    // rs: qq-partner combine; lanes qq==0 store 8 consecutive floats
    #pragma unroll
    for (int j = 0; j < 8; ++j) rs[j] += __shfl_xor(rs[j], 32, 64);
    if (qq == 0) {
        float* dst = part + (qc * F + f) * C + p0;
        *(float4*)dst       = make_float4(rs[0], rs[1], rs[2], rs[3]);
        *(float4*)(dst + 4) = make_float4(rs[4], rs[5], rs[6], rs[7]);
    }

    // gram: block-reduce the 4 waves' C fragments (C layout: col=lane&15,
    // row=(lane>>4)*4+reg -- HW-measured m89)
    {
        const int col = lane & 15, r0 = (lane >> 4) * 4;
        #pragma unroll
        for (int r = 0; r < 4; ++r)
            red[wave * 256 + (r0 + r) * 16 + col] = acc[r];
    }
    __syncthreads();
    gpart[blockIdx.x * 256 + tid] =
        red[tid] + red[256 + tid] + red[512 + tid] + red[768 + tid];
}

// 128 blocks x 256. Block b owns 32 p: reduce 32 rs-chunks -> s_f(p), form
// D/T (wave 0); threads [64,136) reduce this block's 8 gpart rows for the
// 72 needed gram cells (36 per p-batch block).
__global__ __launch_bounds__(256) void sred_kernel(const float* __restrict__ part,
                                                   const float* __restrict__ gpart,
                                                   float* __restrict__ sout) {
    __shared__ float sp[8][F][32];
    const int tid = threadIdx.x;
    const int pi  = tid & 31;
    const int qg  = tid >> 5;
    const int b   = blockIdx.x;
    const int p   = b * 32 + pi;

    float acc[F];
    #pragma unroll
    for (int f = 0; f < F; ++f) acc[f] = 0.0f;
    #pragma unroll
    for (int q4 = 0; q4 < NQC / 8; ++q4) {
        const int qc = qg * (NQC / 8) + q4;
        #pragma unroll
        for (int f = 0; f < F; ++f) acc[f] += part[(qc * F + f) * C + p];
    }
    #pragma unroll
    for (int f = 0; f < F; ++f) sp[qg][f][pi] = acc[f];
    __syncthreads();

    if (tid < 64) {
        float vals[44];                 // D[36] | T[8]
        if (tid < 32) {
            float sv[F];
            #pragma unroll
            for (int f = 0; f < F; ++f) {
                float s = 0.f;
                #pragma unroll
                for (int g2 = 0; g2 < 8; ++g2) s += sp[g2][f][pi];
                sv[f] = s;
            }
            int k = 0;
            #pragma unroll
            for (int i = 0; i < F; ++i)
                #pragma unroll
                for (int j = i; j < F; ++j) { vals[k] = sv[i] * sv[j]; ++k; }
            #pragma unroll
            for (int f2 = 0; f2 < F; ++f2) vals[36 + f2] = sv[f2];
        } else {
            #pragma unroll
            for (int k = 0; k < 44; ++k) vals[k] = 0.f;
        }
        #pragma unroll
        for (int k = 0; k < 44; ++k) vals[k] = wave_reduce(vals[k]);
        if (tid == 0) {
            #pragma unroll
            for (int k = 0; k < 44; ++k) sout[b * SO + k] = vals[k];
        }
    } else if (tid < 64 + 72) {
        const int e  = tid - 64;
        const int eb = (e >= 36) ? e - 36 : e;
        int i = 0, j = eb;                          // unrank i<=j pair
        while (j >= F - i) { j -= F - i; ++i; }
        j += i;
        const int ci = (e >= 36) ? (8 + i) * 16 + (8 + j) : i * 16 + j;
        float s = 0.f;
        #pragma unroll
        for (int r = 0; r < 8; ++r) s += gpart[(b * 8 + r) * 256 + ci];
        sout[b * SO + 44 + e] = s;
    }
}

__global__ __launch_bounds__(256) void finish_kernel(const float* __restrict__ sout,
                                                     float* __restrict__ out) {
    // A: D[0,36) | T[36,44) | G_b0[44,80) | G_b1[80,116)
    __shared__ float fA[SO][2];
    __shared__ float A[SO];
    const int tid = threadIdx.x;
    if (tid < SO * 2) {
        const int colx = tid >> 1, h = tid & 1;
        float s = 0.f;
        #pragma unroll 16
        for (int i = 0; i < NSB / 2; ++i)
            s += sout[(h * (NSB / 2) + i) * SO + colx];
        fA[colx][h] = s;
    }
    __syncthreads();
    if (tid < SO) A[tid] = fA[tid][0] + fA[tid][1];
    __syncthreads();
    if (tid == 0) {
        const float invC  = 1.0f / (float)C;   // 2^-12, exact
        const float invC2 = invC * invC;       // 2^-24, exact
        float dcov[NPAIR], diag[F];
        int k = 0;
        for (int i = 0; i < F; ++i)
            for (int j = i; j < F; ++j) {
                const float G = A[44 + k] + A[80 + k];   // two p-batch blocks
                // S_ij = G/C^2 - 2 D/C^3 + T_i T_j / C^4
                const float S = G * invC2 - 2.0f * A[k] * invC2 * invC
                              + (A[36 + i] * invC2) * (A[36 + j] * invC2);
                const float dc = __builtin_amdgcn_sqrtf(fmaxf(S, 0.0f) + EPSF);
                dcov[k] = dc;
                if (i == j) diag[i] = dc;
                ++k;
            }
        float cor = 0.f;
        k = 0;
        for (int i = 0; i < F; ++i)
            for (int j = i; j < F; ++j) {
                if (j > i)
                    cor += dcov[k] * __builtin_amdgcn_rcpf(
                               __builtin_amdgcn_sqrtf(diag[i] * diag[j] + EPSF));
                ++k;
            }
        out[0] = cor;
    }
}

extern "C" void kernel_launch(void* const* d_in, const int* in_sizes, int n_in,
                              void* d_out, int out_size, void* d_ws, size_t ws_size,
                              hipStream_t stream) {
    const float* x = (const float*)d_in[0];
    float* part  = (float*)d_ws;
    float* gpart = part + WS_PART;
    float* sout  = gpart + WS_GP;
    float* out   = (float*)d_out;

    hipLaunchKernelGGL(gramrs_kernel, dim3(NBLK), dim3(256), 0, stream, x, part, gpart);
    hipLaunchKernelGGL(sred_kernel,   dim3(NSB),  dim3(256), 0, stream, part, gpart, sout);
    hipLaunchKernelGGL(finish_kernel, dim3(1),    dim3(256), 0, stream, sout, out);
}

// Round 12
// 70.932 us; speedup vs baseline: 1.3405x; 1.0799x over previous
//
#include <hip/hip_runtime.h>
#include <math.h>

#define F 8
#define C 4096
#define NPAIR 36
#define EPSF 1e-8f

#define QCH 128              // q per block
#define NQC (C / QCH)        // 32 q-chunks
#define NPG 32               // p-groups of 128 (4 waves x 32 p)
#define NBLK (NPG * NQC)     // 1024 blocks = 4/CU
#define XSROW 132            // 128 + 4 pad (132 = 4*33: float4-aligned rows)

#define NSB 128              // sred blocks
#define SO 116               // sout: D[36] | T[8] | G_b0[36] | G_b1[36]

// ws: part[NQC][F][C] rs-partials (4 MB) | gpart[NBLK][256] C-frags (1 MB) | sout
#define WS_PART (NQC * F * C)
#define WS_GP   (NBLK * 256)

typedef __attribute__((ext_vector_type(8))) short short8v;
typedef __attribute__((ext_vector_type(4))) float f32x4;

__device__ __forceinline__ float wave_reduce(float v) {
    #pragma unroll
    for (int off = 32; off > 0; off >>= 1) v += __shfl_down(v, off, 64);
    return v;
}

// MFMA gram + MFMA rs (indicator-B), fused. Wave = 32 p x 128 q.
// Lane decode: f=lane&7, b=bit3 (p-batch), hi=bit4 (p-octet), qq=bit5.
// q-mapping: lane's q = 64*qq + s (contiguous -> ds_read_b128 per 4 steps).
// Gram: same frag as A and B => C diag 8x8 blocks = per-batch factor grams
// (enumeration-invariant). rs: D_rs = |d| . IND where IND[k][col] =
// delta(pslot(k), col), pslot(k=(g,e)) = 8*(g&1)+e -> D_rs[f+8b][pslot] =
// sum_q |d_f(p,q)| in f32 (products vs exact 1.0). Replaces 8 VALU adds +
// shfl combine per step with 1 MFMA.
__global__ __launch_bounds__(256) void gramrs_kernel(const float* __restrict__ x,
                                                     float* __restrict__ part,
                                                     float* __restrict__ gpart) {
    __shared__ __align__(16) float xs[F * XSROW];   // 4.2 KB q-slice
    __shared__ float red[4 * 256];                  // 4 KB C-frag reduce
    const int tid  = threadIdx.x;
    const int lane = tid & 63;
    const int wave = tid >> 6;
    const int pg = blockIdx.x >> 5;                 // NQC == 32
    const int qc = blockIdx.x & 31;
    const int Q0 = qc * QCH;

    {   // stage q-slice: 8 factors x 32 float4 = 256 threads, one each
        const int sf = tid >> 5, si = tid & 31;
        *(float4*)(xs + sf * XSROW + 4 * si) =
            *(const float4*)(x + sf * C + Q0 + 4 * si);
    }

    const int f  = lane & 7;
    const int b  = (lane >> 3) & 1;
    const int hi = (lane >> 4) & 1;
    const int qq = (lane >> 5) & 1;
    const int pgbase = (pg * 4 + wave) * 32;
    const int p0 = pgbase + 16 * b + 8 * hi;

    float xp[8];
    *(float4*)&xp[0] = *(const float4*)(x + f * C + p0);
    *(float4*)&xp[4] = *(const float4*)(x + f * C + p0 + 4);

    // indicator B-frag: lane (col=lane&15, g=lane>>4) element e is bf16 1.0
    // iff 8*(g&1)+e == col, else 0. At most one nonzero per lane.
    union { unsigned u[4]; short8v v; } ind;
    {
        const int col = lane & 15, gg = lane >> 4;
        const int ea  = col - 8 * (gg & 1);         // active e, or out of range
        #pragma unroll
        for (int t = 0; t < 4; ++t) {
            const unsigned lo = (ea == 2 * t)     ? 0x3F80u : 0u;
            const unsigned hb = (ea == 2 * t + 1) ? 0x3F80u : 0u;
            ind.u[t] = lo | (hb << 16);
        }
    }

    f32x4 acc    = {0.f, 0.f, 0.f, 0.f};
    f32x4 acc_rs = {0.f, 0.f, 0.f, 0.f};

    __syncthreads();

    const float* xrow = xs + f * XSROW + 64 * qq;   // contiguous 64 q for this lane
    #pragma unroll 4
    for (int s4 = 0; s4 < 16; ++s4) {
        const float4 q4 = *(const float4*)(xrow + 4 * s4);
        #pragma unroll
        for (int u = 0; u < 4; ++u) {
            const float xq = (u == 0) ? q4.x : (u == 1) ? q4.y : (u == 2) ? q4.z : q4.w;
            float d[8];
            #pragma unroll
            for (int j = 0; j < 8; ++j) d[j] = xq - xp[j];
            union { unsigned u32[4]; short8v v; } fr;
            #pragma unroll
            for (int t = 0; t < 4; ++t)
                asm("v_cvt_pk_bf16_f32 %0, abs(%1), abs(%2)"
                    : "=v"(fr.u32[t]) : "v"(d[2 * t]), "v"(d[2 * t + 1]));
            acc    = __builtin_amdgcn_mfma_f32_16x16x32_bf16(fr.v, fr.v, acc, 0, 0, 0);
            acc_rs = __builtin_amdgcn_mfma_f32_16x16x32_bf16(fr.v, ind.v, acc_rs, 0, 0, 0);
        }
    }

    // rs extraction: C layout col=lane&15 (pslot), row=(lane>>4)*4+r = f+8b
    {
        const int pslot = lane & 15;
        #pragma unroll
        for (int r = 0; r < 4; ++r) {
            const int row = (lane >> 4) * 4 + r;
            const int ff = row & 7, bb = row >> 3;
            part[(qc * F + ff) * C + (pgbase + 16 * bb + pslot)] = acc_rs[r];
        }
    }

    // gram: block-reduce the 4 waves' C fragments
    {
        const int col = lane & 15, r0 = (lane >> 4) * 4;
        #pragma unroll
        for (int r = 0; r < 4; ++r)
            red[wave * 256 + (r0 + r) * 16 + col] = acc[r];
    }
    __syncthreads();
    gpart[blockIdx.x * 256 + tid] =
        red[tid] + red[256 + tid] + red[512 + tid] + red[768 + tid];
}

// 128 blocks x 256. Block b owns 32 p: reduce 32 rs-chunks -> s_f(p), form
// D/T (wave 0); threads [64,136) reduce this block's 8 gpart rows for the
// 72 needed gram cells (36 per p-batch block).
__global__ __launch_bounds__(256) void sred_kernel(const float* __restrict__ part,
                                                   const float* __restrict__ gpart,
                                                   float* __restrict__ sout) {
    __shared__ float sp[8][F][32];
    const int tid = threadIdx.x;
    const int pi  = tid & 31;
    const int qg  = tid >> 5;
    const int b   = blockIdx.x;
    const int p   = b * 32 + pi;

    float acc[F];
    #pragma unroll
    for (int f = 0; f < F; ++f) acc[f] = 0.0f;
    #pragma unroll
    for (int q4 = 0; q4 < NQC / 8; ++q4) {
        const int qc = qg * (NQC / 8) + q4;
        #pragma unroll
        for (int f = 0; f < F; ++f) acc[f] += part[(qc * F + f) * C + p];
    }
    #pragma unroll
    for (int f = 0; f < F; ++f) sp[qg][f][pi] = acc[f];
    __syncthreads();

    if (tid < 64) {
        float vals[44];                 // D[36] | T[8]
        if (tid < 32) {
            float sv[F];
            #pragma unroll
            for (int f = 0; f < F; ++f) {
                float s = 0.f;
                #pragma unroll
                for (int g2 = 0; g2 < 8; ++g2) s += sp[g2][f][pi];
                sv[f] = s;
            }
            int k = 0;
            #pragma unroll
            for (int i = 0; i < F; ++i)
                #pragma unroll
                for (int j = i; j < F; ++j) { vals[k] = sv[i] * sv[j]; ++k; }
            #pragma unroll
            for (int f2 = 0; f2 < F; ++f2) vals[36 + f2] = sv[f2];
        } else {
            #pragma unroll
            for (int k = 0; k < 44; ++k) vals[k] = 0.f;
        }
        #pragma unroll
        for (int k = 0; k < 44; ++k) vals[k] = wave_reduce(vals[k]);
        if (tid == 0) {
            #pragma unroll
            for (int k = 0; k < 44; ++k) sout[b * SO + k] = vals[k];
        }
    } else if (tid < 64 + 72) {
        const int e  = tid - 64;
        const int eb = (e >= 36) ? e - 36 : e;
        int i = 0, j = eb;                          // unrank i<=j pair
        while (j >= F - i) { j -= F - i; ++i; }
        j += i;
        const int ci = (e >= 36) ? (8 + i) * 16 + (8 + j) : i * 16 + j;
        float s = 0.f;
        #pragma unroll
        for (int r = 0; r < 8; ++r) s += gpart[(b * 8 + r) * 256 + ci];
        sout[b * SO + 44 + e] = s;
    }
}

__global__ __launch_bounds__(256) void finish_kernel(const float* __restrict__ sout,
                                                     float* __restrict__ out) {
    // A: D[0,36) | T[36,44) | G_b0[44,80) | G_b1[80,116)
    __shared__ float fA[SO][2];
    __shared__ float A[SO];
    const int tid = threadIdx.x;
    if (tid < SO * 2) {
        const int colx = tid >> 1, h = tid & 1;
        float s = 0.f;
        #pragma unroll 16
        for (int i = 0; i < NSB / 2; ++i)
            s += sout[(h * (NSB / 2) + i) * SO + colx];
        fA[colx][h] = s;
    }
    __syncthreads();
    if (tid < SO) A[tid] = fA[tid][0] + fA[tid][1];
    __syncthreads();
    if (tid == 0) {
        const float invC  = 1.0f / (float)C;   // 2^-12, exact
        const float invC2 = invC * invC;       // 2^-24, exact
        float dcov[NPAIR], diag[F];
        int k = 0;
        for (int i = 0; i < F; ++i)
            for (int j = i; j < F; ++j) {
                const float G = A[44 + k] + A[80 + k];   // two p-batch blocks
                // S_ij = G/C^2 - 2 D/C^3 + T_i T_j / C^4
                const float S = G * invC2 - 2.0f * A[k] * invC2 * invC
                              + (A[36 + i] * invC2) * (A[36 + j] * invC2);
                const float dc = __builtin_amdgcn_sqrtf(fmaxf(S, 0.0f) + EPSF);
                dcov[k] = dc;
                if (i == j) diag[i] = dc;
                ++k;
            }
        float cor = 0.f;
        k = 0;
        for (int i = 0; i < F; ++i)
            for (int j = i; j < F; ++j) {
                if (j > i)
                    cor += dcov[k] * __builtin_amdgcn_rcpf(
                               __builtin_amdgcn_sqrtf(diag[i] * diag[j] + EPSF));
                ++k;
            }
        out[0] = cor;
    }
}

extern "C" void kernel_launch(void* const* d_in, const int* in_sizes, int n_in,
                              void* d_out, int out_size, void* d_ws, size_t ws_size,
                              hipStream_t stream) {
    const float* x = (const float*)d_in[0];
    float* part  = (float*)d_ws;
    float* gpart = part + WS_PART;
    float* sout  = gpart + WS_GP;
    float* out   = (float*)d_out;

    hipLaunchKernelGGL(gramrs_kernel, dim3(NBLK), dim3(256), 0, stream, x, part, gpart);
    hipLaunchKernelGGL(sred_kernel,   dim3(NSB),  dim3(256), 0, stream, part, gpart, sout);
    hipLaunchKernelGGL(finish_kernel, dim3(1),    dim3(256), 0, stream, sout, out);
}